// Round 8
// baseline (3181.638 us; speedup 1.0000x reference)
//
#include <hip/hip_runtime.h>
#include <stdint.h>

#define N_ATOMS 8192
#define EMBED   32
#define DEPTHN  10

// ---------------------------------------------------------------------------
// adjacency rows [row0, row0+grid) -> bitmask (absolute row index).
// LDS-staged read-all-then-write-all: safe even when mask region aliases the
// tail of A (descending-phase fallback).
// ---------------------------------------------------------------------------
__global__ __launch_bounds__(256) void k_preA(const int* __restrict__ A,
                                              unsigned long long* __restrict__ mask,
                                              int row0)
{
    const int i = row0 + blockIdx.x;
    const int t = threadIdx.x, w = t >> 6, l = t & 63;
    const int* row = A + (size_t)i * N_ATOMS;
    __shared__ unsigned long long lm[128];
    #pragma unroll
    for (int k = 0; k < 32; ++k){
        int j = k*256 + t;
        unsigned long long m = __ballot(row[j] != 0);
        if (l == 0) lm[k*4 + w] = m;
    }
    __syncthreads();
    if (t < 128) mask[(size_t)i*128 + t] = lm[t];
}

// ---------------------------------------------------------------------------
__global__ __launch_bounds__(256) void k_deg(const unsigned* __restrict__ mask,
                                             float* __restrict__ deg,
                                             float* __restrict__ invdeg)
{
    int i = blockIdx.x*256 + threadIdx.x;
    if (i >= N_ATOMS) return;
    const unsigned* mr = mask + (size_t)i*256;
    int cnt = 0;
    #pragma unroll 8
    for (int w = 0; w < 256; ++w) cnt += __popc(mr[w]);
    deg[i] = (float)cnt;
    invdeg[i] = 1.0f / fmaxf((float)cnt, 1.0f);
}

// ---------------------------------------------------------------------------
// setup: h0 gather, Wc = Wih@msgW [10,96,64], bc = Wih@msg_b + bih [10,96].
// ---------------------------------------------------------------------------
__global__ __launch_bounds__(256) void k_setup(
    const int* __restrict__ af, const float* __restrict__ atom_emb,
    const float* __restrict__ msgW, const float* __restrict__ msgb,
    const float* __restrict__ Wih, const float* __restrict__ bih,
    float* __restrict__ hA, float* __restrict__ Wc, float* __restrict__ bc)
{
    const int blk = blockIdx.x, t = threadIdx.x;
    if (blk < 1024){                       // h0: 8192*32
        int idx = blk*256 + t;
        hA[idx] = atom_emb[af[idx >> 5]*EMBED + (idx & 31)];
    } else if (blk < 1264){                // Wc: 10*96*64, K=256
        int o = (blk-1024)*256 + t;
        int d = o / 6144, r = o % 6144, g = r >> 6, e = r & 63;
        const float* wi = Wih  + (size_t)(d*96 + g)*256;
        const float* mw = msgW + (size_t)d*256*64 + e;
        float acc = 0.f;
        for (int hh = 0; hh < 256; ++hh) acc += wi[hh] * mw[hh*64];
        Wc[o] = acc;
    } else {                               // bc: 10*96
        int o = (blk-1264)*256 + t;
        if (o < 960){
            int d = o / 96;
            const float* wi = Wih + (size_t)o*256;   // o = d*96+g
            const float* mb = msgb + d*256;
            float acc = 0.f;
            for (int hh = 0; hh < 256; ++hh) acc += wi[hh] * mb[hh];
            bc[o] = acc + bih[o];
        }
    }
}

// ---------------------------------------------------------------------------
// per depth: neighbor-sum partials (f32 VALU, straight-line-verified).
// grid = 1024 (8 col-chunks x 128 atom-tiles of 64), 256 thr = 4 waves.
// ---------------------------------------------------------------------------
__global__ __launch_bounds__(256) void k_nei(const float* __restrict__ hcur,
                                             const unsigned* __restrict__ mask,
                                             float* __restrict__ neipart)
{
    const int jc = blockIdx.x >> 7;
    const int mb = blockIdx.x & 127;
    const int t = threadIdx.x;
    const int w = t >> 6, lane = t & 63;
    const int row = mb*64 + lane;
    const int j0 = jc*1024 + w*256;

    const unsigned* mrow = mask + (size_t)row*256;
    float acc[32];
    #pragma unroll
    for (int e = 0; e < 32; ++e) acc[e] = 0.f;

    #pragma unroll 1
    for (int wdi = 0; wdi < 8; ++wdi){
        unsigned mw = mrow[(j0 >> 5) + wdi];
        #pragma unroll 4
        for (int b = 0; b < 32; ++b){
            float bf = (float)((mw >> b) & 1u);
            const float4* hp = (const float4*)(hcur + (size_t)(j0 + wdi*32 + b)*EMBED);
            #pragma unroll
            for (int r = 0; r < 8; ++r){
                float4 v = hp[r];
                acc[r*4+0] += bf*v.x; acc[r*4+1] += bf*v.y;
                acc[r*4+2] += bf*v.z; acc[r*4+3] += bf*v.w;
            }
        }
    }

    __shared__ float red[4*64*32];
    #pragma unroll
    for (int r = 0; r < 8; ++r)
        *(float4*)&red[((w*64 + lane)*32) + r*4] =
            make_float4(acc[r*4], acc[r*4+1], acc[r*4+2], acc[r*4+3]);
    __syncthreads();

    const int a = t >> 2, seg = t & 3;
    float* outp = neipart + (size_t)jc * N_ATOMS * EMBED
                + (size_t)(mb*64 + a)*EMBED + seg*8;
    #pragma unroll
    for (int i = 0; i < 8; ++i){
        int off = a*32 + seg*8 + i;
        outp[i] = red[off] + red[2048 + off] + red[4096 + off] + red[6144 + off];
    }
}

// ---------------------------------------------------------------------------
// per depth: fused message+GRU (combined weights). 128 blocks x 512 thr.
// Output h written as FLOAT32 (harness output dtype is f32).
// ---------------------------------------------------------------------------
__global__ __launch_bounds__(512) void k_gru(
    const float* __restrict__ hin, float* __restrict__ hout,
    const float* __restrict__ neipart,
    const float* __restrict__ invdeg, const float* __restrict__ deg,
    const float* __restrict__ Wc, const float* __restrict__ bc,
    const float* __restrict__ bihf, const float* __restrict__ bhhf,
    const float* __restrict__ Whhf,
    float* __restrict__ out0, int last)
{
    const int w = threadIdx.x >> 6, lane = threadIdx.x & 63;
    const int atom = blockIdx.x*64 + lane;
    float x[64];
    const float4* hp = (const float4*)(hin + (size_t)atom*EMBED);
    #pragma unroll
    for (int r = 0; r < 8; ++r){
        float4 v = hp[r];
        x[r*4+0]=v.x; x[r*4+1]=v.y; x[r*4+2]=v.z; x[r*4+3]=v.w;
    }
    const float idg = invdeg[atom];
    const bool nz = deg[atom] > 0.f;
    #pragma unroll
    for (int r = 0; r < 8; ++r){
        float sx=0.f, sy=0.f, sz=0.f, sw=0.f;
        #pragma unroll
        for (int qq = 0; qq < 8; ++qq){
            const float4* pp = (const float4*)(neipart + ((size_t)qq*N_ATOMS + atom)*EMBED);
            float4 v = pp[r];
            sx += v.x; sy += v.y; sz += v.z; sw += v.w;
        }
        x[32+r*4+0] = sx*idg; x[32+r*4+1] = sy*idg;
        x[32+r*4+2] = sz*idg; x[32+r*4+3] = sw*idg;
    }
    #pragma unroll
    for (int jj = 0; jj < 4; ++jj){
        const int j = w*4 + jj;
        const float* wr = Wc + j*64;
        const float* wz = Wc + (32+j)*64;
        const float* wn = Wc + (64+j)*64;
        float gr=0.f, gz=0.f, gn=0.f;
        #pragma unroll
        for (int e = 0; e < 64; ++e){ gr += wr[e]*x[e]; gz += wz[e]*x[e]; gn += wn[e]*x[e]; }
        if (nz){ gr += bc[j]; gz += bc[32+j]; gn += bc[64+j]; }
        else   { gr  = bihf[j]; gz = bihf[32+j]; gn = bihf[64+j]; }
        const float* vr = Whhf + j*32;
        const float* vz = Whhf + (32+j)*32;
        const float* vn = Whhf + (64+j)*32;
        float hr=bhhf[j], hz=bhhf[32+j], hn=bhhf[64+j];
        #pragma unroll
        for (int e = 0; e < 32; ++e){ hr += vr[e]*x[e]; hz += vz[e]*x[e]; hn += vn[e]*x[e]; }
        float rg = 1.f/(1.f + expf(-(gr+hr)));
        float zg = 1.f/(1.f + expf(-(gz+hz)));
        float ng = tanhf(gn + rg*hn);
        float hnew = (1.f - zg)*ng + zg*x[j];
        hout[(size_t)atom*EMBED + j] = hnew;
        if (last) out0[(size_t)atom*EMBED + j] = hnew;
    }
}

// ---------------------------------------------------------------------------
__global__ __launch_bounds__(256) void k_bond(const int* __restrict__ bfeat,
                                              const float* __restrict__ bondf,
                                              float* __restrict__ out1)
{
    int idx = blockIdx.x*256 + threadIdx.x;
    out1[idx] = bondf[bfeat[idx >> 5]*EMBED + (idx & 31)];
}

// ---------------------------------------------------------------------------
__global__ __launch_bounds__(256) void k_pool(
    const float* __restrict__ h, const int* __restrict__ batch,
    const float* __restrict__ poolW, const float* __restrict__ poolb,
    float* __restrict__ out2)
{
    const int b = blockIdx.x, t = threadIdx.x;
    int lo, hi;
    { int l = 0, r = N_ATOMS; while (l < r){ int m = (l+r)>>1; if (batch[m] < b)   l = m+1; else r = m; } lo = l; }
    { int l = 0, r = N_ATOMS; while (l < r){ int m = (l+r)>>1; if (batch[m] < b+1) l = m+1; else r = m; } hi = l; }
    const int cnt = hi - lo;
    __shared__ float ps[8][32];
    __shared__ float mean[32];
    const int e = t & 31, g = t >> 5;
    float acc = 0.f;
    for (int a = lo + g; a < hi; a += 8) acc += h[(size_t)a*EMBED + e];
    ps[g][e] = acc; __syncthreads();
    if (t < 32){
        float s = 0.f;
        #pragma unroll
        for (int gg = 0; gg < 8; ++gg) s += ps[gg][t];
        mean[t] = (cnt > 0) ? s / (float)cnt : 0.f;
    }
    __syncthreads();
    float emb = poolb[t];
    #pragma unroll
    for (int ee = 0; ee < 32; ++ee) emb += mean[ee] * poolW[t*32 + ee];
    out2[b*256 + t] = emb;
}

// ---------------------------------------------------------------------------
extern "C" void kernel_launch(void* const* d_in, const int* in_sizes, int n_in,
                              void* d_out, int out_size, void* d_ws, size_t ws_size,
                              hipStream_t stream)
{
    (void)in_sizes; (void)n_in; (void)out_size;
    const int* af   = (const int*)d_in[0];
    const int* bfe  = (const int*)d_in[1];
    const int* A    = (const int*)d_in[2];
    const int* bidx = (const int*)d_in[3];
    const float* atom_emb = (const float*)d_in[4];
    const float* bond_emb = (const float*)d_in[5];
    const float* msgW  = (const float*)d_in[6];
    const float* msgb  = (const float*)d_in[7];
    const float* Wih   = (const float*)d_in[8];
    const float* Whh   = (const float*)d_in[9];
    const float* bih   = (const float*)d_in[10];
    const float* bhh   = (const float*)d_in[11];
    const float* poolW = (const float*)d_in[12];
    const float* poolb = (const float*)d_in[13];

    // outputs are FLOAT32: h [8192*32] | bond [16384*32] | graph [256*256]
    float* out0 = (float*)d_out;
    float* out1 = out0 + 262144;
    float* out2 = out1 + 524288;

    // large scratch lives in the dead-after-preA adjacency buffer (A head)
    char* Ab = (char*)d_in[2];
    float* hA      = (float*)(Ab + 0);              // 1 MiB
    float* hB      = (float*)(Ab + 1048576);        // 1 MiB
    float* Wc      = (float*)(Ab + 2621440);        // 240 KiB
    float* bc      = (float*)(Ab + 2867200);        // 3.84 KiB
    float* neipart = (float*)(Ab + 4194304);        // 8 MiB, ends 12582912
    float* deg     = (float*)(Ab + 13107200);       // 32 KiB
    float* invdeg  = (float*)(Ab + 13139968);       // 32 KiB

    unsigned long long* mask;
    int wsok = (ws_size >= 8388608) ? 1 : 0;
    if (wsok){
        mask = (unsigned long long*)d_ws;           // 8 MiB in workspace
        k_preA<<<dim3(8192), dim3(256), 0, stream>>>(A, mask, 0);
    } else {
        // A-tail fallback: mask[i] at byte 260046848 + i*1024 overlays rows
        // 7936..8191; descending phases ensure writes only touch rows whose
        // data has already been consumed (k_preA stages via LDS).
        mask = (unsigned long long*)(Ab + 260046848);
        k_preA<<<dim3(1),    dim3(256), 0, stream>>>(A, mask, 8191);
        k_preA<<<dim3(7),    dim3(256), 0, stream>>>(A, mask, 8184);
        k_preA<<<dim3(248),  dim3(256), 0, stream>>>(A, mask, 7936);
        k_preA<<<dim3(7936), dim3(256), 0, stream>>>(A, mask, 0);
    }
    k_deg<<<dim3(32), dim3(256), 0, stream>>>((const unsigned*)mask, deg, invdeg);
    k_setup<<<dim3(1268), dim3(256), 0, stream>>>(af, atom_emb, msgW, msgb,
        Wih, bih, hA, Wc, bc);

    float* hin = hA; float* hout = hB;
    for (int d = 0; d < DEPTHN; ++d){
        k_nei<<<dim3(1024), dim3(256), 0, stream>>>(hin, (const unsigned*)mask, neipart);
        k_gru<<<dim3(128), dim3(512), 0, stream>>>(hin, hout, neipart, invdeg, deg,
            Wc + d*6144, bc + d*96, bih + d*96, bhh + d*96, Whh + d*3072,
            out0, (d == DEPTHN-1) ? 1 : 0);
        float* tmp = hin; hin = hout; hout = tmp;
    }
    k_bond<<<dim3(2048), dim3(256), 0, stream>>>(bfe, bond_emb, out1);
    k_pool<<<dim3(256), dim3(256), 0, stream>>>(hin, bidx, poolW, poolb, out2);
}

// Round 9
// 911.923 us; speedup vs baseline: 3.4889x; 3.4889x over previous
//
#include <hip/hip_runtime.h>
#include <stdint.h>

#define N_ATOMS 8192
#define EMBED   32
#define DEPTHN  10

typedef short bf16x8 __attribute__((ext_vector_type(8)));
typedef float f32x4  __attribute__((ext_vector_type(4)));

__device__ __forceinline__ unsigned short f2bf(float f){
    unsigned u = __builtin_bit_cast(unsigned, f);
    u = u + 0x7FFFu + ((u >> 16) & 1u);
    return (unsigned short)(u >> 16);
}

// ---------------------------------------------------------------------------
// adjacency rows [row0, row0+grid) -> bitmask. LDS-staged read-all-then-
// write-all (safe under A-tail aliasing fallback).
// ---------------------------------------------------------------------------
__global__ __launch_bounds__(256) void k_preA(const int* __restrict__ A,
                                              unsigned long long* __restrict__ mask,
                                              int row0)
{
    const int i = row0 + blockIdx.x;
    const int t = threadIdx.x, w = t >> 6, l = t & 63;
    const int* row = A + (size_t)i * N_ATOMS;
    __shared__ unsigned long long lm[128];
    #pragma unroll
    for (int k = 0; k < 32; ++k){
        int j = k*256 + t;
        unsigned long long m = __ballot(row[j] != 0);
        if (l == 0) lm[k*4 + w] = m;
    }
    __syncthreads();
    if (t < 128) mask[(size_t)i*128 + t] = lm[t];
}

// ---------------------------------------------------------------------------
__global__ __launch_bounds__(256) void k_deg(const unsigned* __restrict__ mask,
                                             float* __restrict__ deg,
                                             float* __restrict__ invdeg)
{
    int i = blockIdx.x*256 + threadIdx.x;
    if (i >= N_ATOMS) return;
    const unsigned* mr = mask + (size_t)i*256;
    int cnt = 0;
    #pragma unroll 8
    for (int w = 0; w < 256; ++w) cnt += __popc(mr[w]);
    deg[i] = (float)cnt;
    invdeg[i] = 1.0f / fmaxf((float)cnt, 1.0f);
}

// ---------------------------------------------------------------------------
// setup: h0 gather (f32 + bf16-transposed), Wc = Wih@msgW, bc = Wih@msg_b+bih.
// ---------------------------------------------------------------------------
__global__ __launch_bounds__(256) void k_setup(
    const int* __restrict__ af, const float* __restrict__ atom_emb,
    const float* __restrict__ msgW, const float* __restrict__ msgb,
    const float* __restrict__ Wih, const float* __restrict__ bih,
    float* __restrict__ hA, unsigned short* __restrict__ hT,
    float* __restrict__ Wc, float* __restrict__ bc)
{
    const int blk = blockIdx.x, t = threadIdx.x;
    if (blk < 1024){                       // h0: 8192*32
        int idx = blk*256 + t;
        int i = idx >> 5, e = idx & 31;
        float v = atom_emb[af[i]*EMBED + e];
        hA[idx] = v;
        hT[(size_t)e*N_ATOMS + i] = f2bf(v);
    } else if (blk < 1264){                // Wc: 10*96*64, K=256
        int o = (blk-1024)*256 + t;
        int d = o / 6144, r = o % 6144, g = r >> 6, e = r & 63;
        const float* wi = Wih  + (size_t)(d*96 + g)*256;
        const float* mw = msgW + (size_t)d*256*64 + e;
        float acc = 0.f;
        for (int hh = 0; hh < 256; ++hh) acc += wi[hh] * mw[hh*64];
        Wc[o] = acc;
    } else {                               // bc: 10*96
        int o = (blk-1264)*256 + t;
        if (o < 960){
            int d = o / 96;
            const float* wi = Wih + (size_t)o*256;   // o = d*96+g
            const float* mb = msgb + d*256;
            float acc = 0.f;
            for (int hh = 0; hh < 256; ++hh) acc += wi[hh] * mb[hh];
            bc[o] = acc + bih[o];
        }
    }
}

// ---------------------------------------------------------------------------
// per depth: neighbor-sum partials via MFMA. grid = 512 (4 K-quarters x 128
// row-blocks of 64). Wave = one 16-row M-tile. A-frag expanded from mask
// bits -> bf16 {0,1}. mfma_f32_16x16x32_bf16 layouts (m89-verified):
//   A[m=lane&15][k=quad*8+j], B[k=quad*8+j][n=lane&15], D[quad*4+r][lane&15].
// mask u32 word W covers columns 32W..32W+31, bit b = column 32W+b
// (bit-for-bit verified by the passing round-8 VALU kernel).
// ---------------------------------------------------------------------------
__global__ __launch_bounds__(256) void k_nei(const unsigned short* __restrict__ hT,
                                             const unsigned* __restrict__ mask,
                                             float* __restrict__ neipart)
{
    __shared__ __align__(16) unsigned short hS[32][520];  // 512-col chunk, +8 pad
    __shared__ unsigned mS[64][17];                       // 64 rows x 16 words, +1 pad
    const int t = threadIdx.x;
    const int q  = blockIdx.x >> 7;     // K quarter (2048 cols)
    const int mb = blockIdx.x & 127;    // row block (64 rows)
    const int bRow = mb * 64;
    const int w = t >> 6, lane = t & 63;
    const int n = lane & 15, quad = lane >> 4;

    f32x4 acc0 = {0.f,0.f,0.f,0.f};
    f32x4 acc1 = {0.f,0.f,0.f,0.f};

    for (int c = 0; c < 4; ++c){
        const int k0 = q*2048 + c*512;
        __syncthreads();
        #pragma unroll
        for (int r = 0; r < 8; ++r){          // stage h^T chunk: 32 x 512 bf16
            int id = t + r*256;
            int e = id >> 6, c8 = id & 63;
            *(uint4*)&hS[e][c8*8] = *(const uint4*)&hT[(size_t)e*N_ATOMS + k0 + c8*8];
        }
        #pragma unroll
        for (int r = 0; r < 4; ++r){          // stage masks: 64 rows x 16 u32
            int id = t + r*256;
            int rr = id >> 4, wd = id & 15;
            mS[rr][wd] = mask[(size_t)(bRow + rr)*256 + q*64 + c*16 + wd];
        }
        __syncthreads();
        #pragma unroll 4
        for (int kk = 0; kk < 16; ++kk){
            unsigned mw = mS[w*16 + n][kk];
            unsigned byt = (mw >> (quad*8)) & 0xFFu;
            union { unsigned u[4]; bf16x8 v; } a;
            a.u[0] = ((byt & 1u)  ? 0x3F80u : 0u) | ((byt & 2u)   ? 0x3F800000u : 0u);
            a.u[1] = ((byt & 4u)  ? 0x3F80u : 0u) | ((byt & 8u)   ? 0x3F800000u : 0u);
            a.u[2] = ((byt & 16u) ? 0x3F80u : 0u) | ((byt & 32u)  ? 0x3F800000u : 0u);
            a.u[3] = ((byt & 64u) ? 0x3F80u : 0u) | ((byt & 128u) ? 0x3F800000u : 0u);
            const int col = kk*32 + quad*8;
            union { uint4 u; bf16x8 v; } b0, b1;
            b0.u = *(const uint4*)&hS[n][col];
            b1.u = *(const uint4*)&hS[16 + n][col];
            acc0 = __builtin_amdgcn_mfma_f32_16x16x32_bf16(a.v, b0.v, acc0, 0, 0, 0);
            acc1 = __builtin_amdgcn_mfma_f32_16x16x32_bf16(a.v, b1.v, acc1, 0, 0, 0);
        }
    }
    float* outp = neipart + (size_t)q * N_ATOMS * EMBED;
    #pragma unroll
    for (int r = 0; r < 4; ++r){
        int row = bRow + w*16 + quad*4 + r;
        outp[(size_t)row*EMBED + n]      = acc0[r];
        outp[(size_t)row*EMBED + 16 + n] = acc1[r];
    }
}

// ---------------------------------------------------------------------------
// per depth: fused message+GRU (combined weights). 128 blocks x 512 thr.
// Wave w: 64 atoms (lane=atom) x gate rows j = w*4..w*4+3 (wave-uniform).
// Writes f32 hout (+ out0 on last depth) and bf16 hT for next depth's MFMA.
// ---------------------------------------------------------------------------
__global__ __launch_bounds__(512) void k_gru(
    const float* __restrict__ hin, float* __restrict__ hout,
    const float* __restrict__ neipart,
    const float* __restrict__ invdeg, const float* __restrict__ deg,
    const float* __restrict__ Wc, const float* __restrict__ bc,
    const float* __restrict__ bihf, const float* __restrict__ bhhf,
    const float* __restrict__ Whhf,
    unsigned short* __restrict__ hT, float* __restrict__ out0, int last)
{
    const int w = threadIdx.x >> 6, lane = threadIdx.x & 63;
    const int atom = blockIdx.x*64 + lane;
    float x[64];
    const float4* hp = (const float4*)(hin + (size_t)atom*EMBED);
    #pragma unroll
    for (int r = 0; r < 8; ++r){
        float4 v = hp[r];
        x[r*4+0]=v.x; x[r*4+1]=v.y; x[r*4+2]=v.z; x[r*4+3]=v.w;
    }
    const float idg = invdeg[atom];
    const bool nz = deg[atom] > 0.f;
    #pragma unroll
    for (int r = 0; r < 8; ++r){
        float sx=0.f, sy=0.f, sz=0.f, sw=0.f;
        #pragma unroll
        for (int qq = 0; qq < 4; ++qq){
            const float4* pp = (const float4*)(neipart + ((size_t)qq*N_ATOMS + atom)*EMBED);
            float4 v = pp[r];
            sx += v.x; sy += v.y; sz += v.z; sw += v.w;
        }
        x[32+r*4+0] = sx*idg; x[32+r*4+1] = sy*idg;
        x[32+r*4+2] = sz*idg; x[32+r*4+3] = sw*idg;
    }
    #pragma unroll
    for (int jj = 0; jj < 4; ++jj){
        const int j = w*4 + jj;
        const float* wr = Wc + j*64;
        const float* wz = Wc + (32+j)*64;
        const float* wn = Wc + (64+j)*64;
        float gr=0.f, gz=0.f, gn=0.f;
        #pragma unroll
        for (int e = 0; e < 64; ++e){ gr += wr[e]*x[e]; gz += wz[e]*x[e]; gn += wn[e]*x[e]; }
        if (nz){ gr += bc[j]; gz += bc[32+j]; gn += bc[64+j]; }
        else   { gr  = bihf[j]; gz = bihf[32+j]; gn = bihf[64+j]; }
        const float* vr = Whhf + j*32;
        const float* vz = Whhf + (32+j)*32;
        const float* vn = Whhf + (64+j)*32;
        float hr=bhhf[j], hz=bhhf[32+j], hn=bhhf[64+j];
        #pragma unroll
        for (int e = 0; e < 32; ++e){ hr += vr[e]*x[e]; hz += vz[e]*x[e]; hn += vn[e]*x[e]; }
        float rg = 1.f/(1.f + expf(-(gr+hr)));
        float zg = 1.f/(1.f + expf(-(gz+hz)));
        float ng = tanhf(gn + rg*hn);
        float hnew = (1.f - zg)*ng + zg*x[j];
        hout[(size_t)atom*EMBED + j] = hnew;
        hT[(size_t)j*N_ATOMS + atom] = f2bf(hnew);
        if (last) out0[(size_t)atom*EMBED + j] = hnew;
    }
}

// ---------------------------------------------------------------------------
__global__ __launch_bounds__(256) void k_bond(const int* __restrict__ bfeat,
                                              const float* __restrict__ bondf,
                                              float* __restrict__ out1)
{
    int idx = blockIdx.x*256 + threadIdx.x;
    out1[idx] = bondf[bfeat[idx >> 5]*EMBED + (idx & 31)];
}

// ---------------------------------------------------------------------------
__global__ __launch_bounds__(256) void k_pool(
    const float* __restrict__ h, const int* __restrict__ batch,
    const float* __restrict__ poolW, const float* __restrict__ poolb,
    float* __restrict__ out2)
{
    const int b = blockIdx.x, t = threadIdx.x;
    int lo, hi;
    { int l = 0, r = N_ATOMS; while (l < r){ int m = (l+r)>>1; if (batch[m] < b)   l = m+1; else r = m; } lo = l; }
    { int l = 0, r = N_ATOMS; while (l < r){ int m = (l+r)>>1; if (batch[m] < b+1) l = m+1; else r = m; } hi = l; }
    const int cnt = hi - lo;
    __shared__ float ps[8][32];
    __shared__ float mean[32];
    const int e = t & 31, g = t >> 5;
    float acc = 0.f;
    for (int a = lo + g; a < hi; a += 8) acc += h[(size_t)a*EMBED + e];
    ps[g][e] = acc; __syncthreads();
    if (t < 32){
        float s = 0.f;
        #pragma unroll
        for (int gg = 0; gg < 8; ++gg) s += ps[gg][t];
        mean[t] = (cnt > 0) ? s / (float)cnt : 0.f;
    }
    __syncthreads();
    float emb = poolb[t];
    #pragma unroll
    for (int ee = 0; ee < 32; ++ee) emb += mean[ee] * poolW[t*32 + ee];
    out2[b*256 + t] = emb;
}

// ---------------------------------------------------------------------------
extern "C" void kernel_launch(void* const* d_in, const int* in_sizes, int n_in,
                              void* d_out, int out_size, void* d_ws, size_t ws_size,
                              hipStream_t stream)
{
    (void)in_sizes; (void)n_in; (void)out_size;
    const int* af   = (const int*)d_in[0];
    const int* bfe  = (const int*)d_in[1];
    const int* A    = (const int*)d_in[2];
    const int* bidx = (const int*)d_in[3];
    const float* atom_emb = (const float*)d_in[4];
    const float* bond_emb = (const float*)d_in[5];
    const float* msgW  = (const float*)d_in[6];
    const float* msgb  = (const float*)d_in[7];
    const float* Wih   = (const float*)d_in[8];
    const float* Whh   = (const float*)d_in[9];
    const float* bih   = (const float*)d_in[10];
    const float* bhh   = (const float*)d_in[11];
    const float* poolW = (const float*)d_in[12];
    const float* poolb = (const float*)d_in[13];

    // outputs are FLOAT32: h [8192*32] | bond [16384*32] | graph [256*256]
    float* out0 = (float*)d_out;
    float* out1 = out0 + 262144;
    float* out2 = out1 + 524288;

    // large scratch lives in the dead-after-preA adjacency buffer (A head)
    char* Ab = (char*)d_in[2];
    float*          hA      = (float*)(Ab + 0);              // 1 MiB
    float*          hB      = (float*)(Ab + 1048576);        // 1 MiB
    unsigned short* hT      = (unsigned short*)(Ab + 2097152); // 512 KiB
    float*          Wc      = (float*)(Ab + 2621440);        // 240 KiB
    float*          bc      = (float*)(Ab + 2867200);        // 3.84 KiB
    float*          neipart = (float*)(Ab + 4194304);        // 4 MiB (4 chunks)
    float*          deg     = (float*)(Ab + 13107200);       // 32 KiB
    float*          invdeg  = (float*)(Ab + 13139968);       // 32 KiB

    unsigned long long* mask;
    int wsok = (ws_size >= 8388608) ? 1 : 0;
    if (wsok){
        mask = (unsigned long long*)d_ws;           // 8 MiB in workspace
        k_preA<<<dim3(8192), dim3(256), 0, stream>>>(A, mask, 0);
    } else {
        // A-tail fallback: descending phases; LDS-staged k_preA makes the
        // row-7936..8191 overlay safe.
        mask = (unsigned long long*)(Ab + 260046848);
        k_preA<<<dim3(1),    dim3(256), 0, stream>>>(A, mask, 8191);
        k_preA<<<dim3(7),    dim3(256), 0, stream>>>(A, mask, 8184);
        k_preA<<<dim3(248),  dim3(256), 0, stream>>>(A, mask, 7936);
        k_preA<<<dim3(7936), dim3(256), 0, stream>>>(A, mask, 0);
    }
    k_deg<<<dim3(32), dim3(256), 0, stream>>>((const unsigned*)mask, deg, invdeg);
    k_setup<<<dim3(1268), dim3(256), 0, stream>>>(af, atom_emb, msgW, msgb,
        Wih, bih, hA, hT, Wc, bc);

    float* hin = hA; float* hout = hB;
    for (int d = 0; d < DEPTHN; ++d){
        k_nei<<<dim3(512), dim3(256), 0, stream>>>(hT, (const unsigned*)mask, neipart);
        k_gru<<<dim3(128), dim3(512), 0, stream>>>(hin, hout, neipart, invdeg, deg,
            Wc + d*6144, bc + d*96, bih + d*96, bhh + d*96, Whh + d*3072,
            hT, out0, (d == DEPTHN-1) ? 1 : 0);
        float* tmp = hin; hin = hout; hout = tmp;
    }
    k_bond<<<dim3(2048), dim3(256), 0, stream>>>(bfe, bond_emb, out1);
    k_pool<<<dim3(256), dim3(256), 0, stream>>>(hin, bidx, poolW, poolb, out2);
}

// Round 10
// 852.063 us; speedup vs baseline: 3.7340x; 1.0703x over previous
//
#include <hip/hip_runtime.h>
#include <stdint.h>

#define N_ATOMS 8192
#define EMBED   32
#define DEPTHN  10

typedef short bf16x8 __attribute__((ext_vector_type(8)));
typedef float f32x4  __attribute__((ext_vector_type(4)));

__device__ __forceinline__ unsigned short f2bf(float f){
    unsigned u = __builtin_bit_cast(unsigned, f);
    u = u + 0x7FFFu + ((u >> 16) & 1u);
    return (unsigned short)(u >> 16);
}

// ---------------------------------------------------------------------------
// adjacency rows [row0, row0+grid) -> bitmask. LDS-staged read-all-then-
// write-all (safe under A-tail aliasing fallback).
// ---------------------------------------------------------------------------
__global__ __launch_bounds__(256) void k_preA(const int* __restrict__ A,
                                              unsigned long long* __restrict__ mask,
                                              int row0)
{
    const int i = row0 + blockIdx.x;
    const int t = threadIdx.x, w = t >> 6, l = t & 63;
    const int* row = A + (size_t)i * N_ATOMS;
    __shared__ unsigned long long lm[128];
    #pragma unroll
    for (int k = 0; k < 32; ++k){
        int j = k*256 + t;
        unsigned long long m = __ballot(row[j] != 0);
        if (l == 0) lm[k*4 + w] = m;
    }
    __syncthreads();
    if (t < 128) mask[(size_t)i*128 + t] = lm[t];
}

// ---------------------------------------------------------------------------
// deg: one wave per row, coalesced 256-B loads, shuffle reduce.
// ---------------------------------------------------------------------------
__global__ __launch_bounds__(256) void k_deg(const unsigned* __restrict__ mask,
                                             float* __restrict__ deg,
                                             float* __restrict__ invdeg)
{
    const int t = threadIdx.x, w = t >> 6, lane = t & 63;
    const int row = blockIdx.x*4 + w;
    const unsigned* mr = mask + (size_t)row*256;
    int cnt = 0;
    #pragma unroll
    for (int k = 0; k < 4; ++k) cnt += __popc(mr[lane + k*64]);
    #pragma unroll
    for (int s = 32; s > 0; s >>= 1) cnt += __shfl_down(cnt, s, 64);
    if (lane == 0){
        deg[row] = (float)cnt;
        invdeg[row] = 1.0f / fmaxf((float)cnt, 1.0f);
    }
}

// ---------------------------------------------------------------------------
// setup: h0 gather (f32 + bf16-transposed), Wc = Wih@msgW, bc = Wih@msg_b+bih.
// ---------------------------------------------------------------------------
__global__ __launch_bounds__(256) void k_setup(
    const int* __restrict__ af, const float* __restrict__ atom_emb,
    const float* __restrict__ msgW, const float* __restrict__ msgb,
    const float* __restrict__ Wih, const float* __restrict__ bih,
    float* __restrict__ hA, unsigned short* __restrict__ hT,
    float* __restrict__ Wc, float* __restrict__ bc)
{
    const int blk = blockIdx.x, t = threadIdx.x;
    if (blk < 1024){                       // h0: 8192*32
        int idx = blk*256 + t;
        int i = idx >> 5, e = idx & 31;
        float v = atom_emb[af[i]*EMBED + e];
        hA[idx] = v;
        hT[(size_t)e*N_ATOMS + i] = f2bf(v);
    } else if (blk < 1264){                // Wc: 10*96*64, K=256
        int o = (blk-1024)*256 + t;
        int d = o / 6144, r = o % 6144, g = r >> 6, e = r & 63;
        const float* wi = Wih  + (size_t)(d*96 + g)*256;
        const float* mw = msgW + (size_t)d*256*64 + e;
        float acc = 0.f;
        for (int hh = 0; hh < 256; ++hh) acc += wi[hh] * mw[hh*64];
        Wc[o] = acc;
    } else {                               // bc: 10*96
        int o = (blk-1264)*256 + t;
        if (o < 960){
            int d = o / 96;
            const float* wi = Wih + (size_t)o*256;   // o = d*96+g
            const float* mb = msgb + d*256;
            float acc = 0.f;
            for (int hh = 0; hh < 256; ++hh) acc += wi[hh] * mb[hh];
            bc[o] = acc + bih[o];
        }
    }
}

// ---------------------------------------------------------------------------
// per depth: neighbor-sum partials via MFMA. grid = 512 (8 K-eighths x 64
// row-blocks of 128). Wave = 32 rows (two 16-row A-tiles sharing each
// B-fragment -> LDS read traffic halved vs 16-row tiling). hT staged via
// global_load_lds width=16 (dest = wave-uniform base + lane*16).
// mfma_f32_16x16x32_bf16 layouts (round-9-verified in this exact pipeline):
//   A[m=lane&15][k=quad*8+j], B[k=quad*8+j][n=lane&15], D[quad*4+r][lane&15].
// ---------------------------------------------------------------------------
__global__ __launch_bounds__(256) void k_nei(const unsigned short* __restrict__ hT,
                                             const unsigned* __restrict__ mask,
                                             float* __restrict__ neipart)
{
    __shared__ __align__(16) unsigned short hS[32][520];  // 512-col chunk
    __shared__ unsigned mS[128][17];                      // 128 rows x 16 words
    const int t = threadIdx.x;
    const int q8 = blockIdx.x >> 6;     // K eighth (1024 cols)
    const int mb = blockIdx.x & 63;     // row block (128 rows)
    const int bRow = mb * 128;
    const int w = t >> 6, lane = t & 63;
    const int n = lane & 15, quad = lane >> 4;
    const int w32 = w * 32;

    f32x4 acc00 = {0.f,0.f,0.f,0.f};    // tile0 (rows w32+0..15),  cols n
    f32x4 acc01 = {0.f,0.f,0.f,0.f};    // tile0, cols 16+n
    f32x4 acc10 = {0.f,0.f,0.f,0.f};    // tile1 (rows w32+16..31), cols n
    f32x4 acc11 = {0.f,0.f,0.f,0.f};    // tile1, cols 16+n

    for (int c = 0; c < 2; ++c){
        const int k0 = q8*1024 + c*512;
        __syncthreads();
        #pragma unroll
        for (int r = 0; r < 8; ++r){          // stage h^T 32x512 via DMA
            int e = w + 4*r;
            const unsigned short* gp = &hT[(size_t)e*N_ATOMS + k0 + lane*8];
            __builtin_amdgcn_global_load_lds(
                (const __attribute__((address_space(1))) void*)gp,
                (__attribute__((address_space(3))) void*)&hS[e][0], 16, 0, 0);
        }
        #pragma unroll
        for (int r = 0; r < 8; ++r){          // stage masks: 128 rows x 16 u32
            int id = t + r*256;
            int rr = id >> 4, wd = id & 15;
            mS[rr][wd] = mask[(size_t)(bRow + rr)*256 + q8*32 + c*16 + wd];
        }
        __syncthreads();
        #pragma unroll 4
        for (int kk = 0; kk < 16; ++kk){
            unsigned mw0 = mS[w32 + n][kk];
            unsigned mw1 = mS[w32 + 16 + n][kk];
            unsigned by0 = (mw0 >> (quad*8)) & 0xFFu;
            unsigned by1 = (mw1 >> (quad*8)) & 0xFFu;
            union { unsigned u[4]; bf16x8 v; } a0, a1;
            a0.u[0] = ((by0 & 1u)  ? 0x3F80u : 0u) | ((by0 & 2u)   ? 0x3F800000u : 0u);
            a0.u[1] = ((by0 & 4u)  ? 0x3F80u : 0u) | ((by0 & 8u)   ? 0x3F800000u : 0u);
            a0.u[2] = ((by0 & 16u) ? 0x3F80u : 0u) | ((by0 & 32u)  ? 0x3F800000u : 0u);
            a0.u[3] = ((by0 & 64u) ? 0x3F80u : 0u) | ((by0 & 128u) ? 0x3F800000u : 0u);
            a1.u[0] = ((by1 & 1u)  ? 0x3F80u : 0u) | ((by1 & 2u)   ? 0x3F800000u : 0u);
            a1.u[1] = ((by1 & 4u)  ? 0x3F80u : 0u) | ((by1 & 8u)   ? 0x3F800000u : 0u);
            a1.u[2] = ((by1 & 16u) ? 0x3F80u : 0u) | ((by1 & 32u)  ? 0x3F800000u : 0u);
            a1.u[3] = ((by1 & 64u) ? 0x3F80u : 0u) | ((by1 & 128u) ? 0x3F800000u : 0u);
            const int col = kk*32 + quad*8;
            union { uint4 u; bf16x8 v; } b0, b1;
            b0.u = *(const uint4*)&hS[n][col];
            b1.u = *(const uint4*)&hS[16 + n][col];
            acc00 = __builtin_amdgcn_mfma_f32_16x16x32_bf16(a0.v, b0.v, acc00, 0, 0, 0);
            acc01 = __builtin_amdgcn_mfma_f32_16x16x32_bf16(a0.v, b1.v, acc01, 0, 0, 0);
            acc10 = __builtin_amdgcn_mfma_f32_16x16x32_bf16(a1.v, b0.v, acc10, 0, 0, 0);
            acc11 = __builtin_amdgcn_mfma_f32_16x16x32_bf16(a1.v, b1.v, acc11, 0, 0, 0);
        }
    }
    float* outp = neipart + (size_t)q8 * N_ATOMS * EMBED;
    #pragma unroll
    for (int r = 0; r < 4; ++r){
        int row0 = bRow + w32 + quad*4 + r;
        int row1 = row0 + 16;
        outp[(size_t)row0*EMBED + n]      = acc00[r];
        outp[(size_t)row0*EMBED + 16 + n] = acc01[r];
        outp[(size_t)row1*EMBED + n]      = acc10[r];
        outp[(size_t)row1*EMBED + 16 + n] = acc11[r];
    }
}

// ---------------------------------------------------------------------------
// per depth: fused message+GRU. 128 blocks x 512 thr. x staged via LDS with
// COALESCED loads (contiguous 8 KiB segments), then per-lane registers.
// Wave w: 64 atoms (lane=atom) x units j = w*4..w*4+3.
// ---------------------------------------------------------------------------
__global__ __launch_bounds__(512) void k_gru(
    const float* __restrict__ hin, float* __restrict__ hout,
    const float* __restrict__ neipart,
    const float* __restrict__ invdeg, const float* __restrict__ deg,
    const float* __restrict__ Wc, const float* __restrict__ bc,
    const float* __restrict__ bihf, const float* __restrict__ bhhf,
    const float* __restrict__ Whhf,
    unsigned short* __restrict__ hT, float* __restrict__ out0, int last)
{
    __shared__ float xs[64][68];
    const int t = threadIdx.x, blk = blockIdx.x;
    {   // stage h: 64 atoms x 32 f, contiguous, coalesced
        float4 v = *(const float4*)&hin[(size_t)blk*2048 + t*4];
        int a = t >> 3, e = (t*4) & 31;
        *(float4*)&xs[a][e] = v;
    }
    {   // stage nei sum over 8 K-eighth partials, coalesced
        float4 s = {0.f,0.f,0.f,0.f};
        #pragma unroll
        for (int q = 0; q < 8; ++q){
            float4 v = *(const float4*)&neipart[(size_t)q*N_ATOMS*EMBED + blk*2048 + t*4];
            s.x += v.x; s.y += v.y; s.z += v.z; s.w += v.w;
        }
        int a = t >> 3, e = (t*4) & 31;
        *(float4*)&xs[a][32 + e] = s;
    }
    __syncthreads();

    const int w = t >> 6, lane = t & 63;
    const int atom = blk*64 + lane;
    const float idg = invdeg[atom];
    const bool nz = deg[atom] > 0.f;
    float x[64];
    #pragma unroll
    for (int r = 0; r < 16; ++r){
        float4 v = *(const float4*)&xs[lane][r*4];
        x[r*4+0]=v.x; x[r*4+1]=v.y; x[r*4+2]=v.z; x[r*4+3]=v.w;
    }
    #pragma unroll
    for (int e = 32; e < 64; ++e) x[e] *= idg;

    #pragma unroll
    for (int jj = 0; jj < 4; ++jj){
        const int j = w*4 + jj;
        const float* wr = Wc + j*64;
        const float* wz = Wc + (32+j)*64;
        const float* wn = Wc + (64+j)*64;
        float gr=0.f, gz=0.f, gn=0.f;
        #pragma unroll
        for (int e = 0; e < 64; ++e){ gr += wr[e]*x[e]; gz += wz[e]*x[e]; gn += wn[e]*x[e]; }
        if (nz){ gr += bc[j]; gz += bc[32+j]; gn += bc[64+j]; }
        else   { gr  = bihf[j]; gz = bihf[32+j]; gn = bihf[64+j]; }
        const float* vr = Whhf + j*32;
        const float* vz = Whhf + (32+j)*32;
        const float* vn = Whhf + (64+j)*32;
        float hr=bhhf[j], hz=bhhf[32+j], hn=bhhf[64+j];
        #pragma unroll
        for (int e = 0; e < 32; ++e){ hr += vr[e]*x[e]; hz += vz[e]*x[e]; hn += vn[e]*x[e]; }
        float rg = 1.f/(1.f + expf(-(gr+hr)));
        float zg = 1.f/(1.f + expf(-(gz+hz)));
        float ng = tanhf(gn + rg*hn);
        float hnew = (1.f - zg)*ng + zg*x[j];
        hout[(size_t)atom*EMBED + j] = hnew;
        hT[(size_t)j*N_ATOMS + atom] = f2bf(hnew);
        if (last) out0[(size_t)atom*EMBED + j] = hnew;
    }
}

// ---------------------------------------------------------------------------
__global__ __launch_bounds__(256) void k_bond(const int* __restrict__ bfeat,
                                              const float* __restrict__ bondf,
                                              float* __restrict__ out1)
{
    int idx = blockIdx.x*256 + threadIdx.x;
    out1[idx] = bondf[bfeat[idx >> 5]*EMBED + (idx & 31)];
}

// ---------------------------------------------------------------------------
__global__ __launch_bounds__(256) void k_pool(
    const float* __restrict__ h, const int* __restrict__ batch,
    const float* __restrict__ poolW, const float* __restrict__ poolb,
    float* __restrict__ out2)
{
    const int b = blockIdx.x, t = threadIdx.x;
    int lo, hi;
    { int l = 0, r = N_ATOMS; while (l < r){ int m = (l+r)>>1; if (batch[m] < b)   l = m+1; else r = m; } lo = l; }
    { int l = 0, r = N_ATOMS; while (l < r){ int m = (l+r)>>1; if (batch[m] < b+1) l = m+1; else r = m; } hi = l; }
    const int cnt = hi - lo;
    __shared__ float ps[8][32];
    __shared__ float mean[32];
    const int e = t & 31, g = t >> 5;
    float acc = 0.f;
    for (int a = lo + g; a < hi; a += 8) acc += h[(size_t)a*EMBED + e];
    ps[g][e] = acc; __syncthreads();
    if (t < 32){
        float s = 0.f;
        #pragma unroll
        for (int gg = 0; gg < 8; ++gg) s += ps[gg][t];
        mean[t] = (cnt > 0) ? s / (float)cnt : 0.f;
    }
    __syncthreads();
    float emb = poolb[t];
    #pragma unroll
    for (int ee = 0; ee < 32; ++ee) emb += mean[ee] * poolW[t*32 + ee];
    out2[b*256 + t] = emb;
}

// ---------------------------------------------------------------------------
extern "C" void kernel_launch(void* const* d_in, const int* in_sizes, int n_in,
                              void* d_out, int out_size, void* d_ws, size_t ws_size,
                              hipStream_t stream)
{
    (void)in_sizes; (void)n_in; (void)out_size;
    const int* af   = (const int*)d_in[0];
    const int* bfe  = (const int*)d_in[1];
    const int* A    = (const int*)d_in[2];
    const int* bidx = (const int*)d_in[3];
    const float* atom_emb = (const float*)d_in[4];
    const float* bond_emb = (const float*)d_in[5];
    const float* msgW  = (const float*)d_in[6];
    const float* msgb  = (const float*)d_in[7];
    const float* Wih   = (const float*)d_in[8];
    const float* Whh   = (const float*)d_in[9];
    const float* bih   = (const float*)d_in[10];
    const float* bhh   = (const float*)d_in[11];
    const float* poolW = (const float*)d_in[12];
    const float* poolb = (const float*)d_in[13];

    // outputs are FLOAT32: h [8192*32] | bond [16384*32] | graph [256*256]
    float* out0 = (float*)d_out;
    float* out1 = out0 + 262144;
    float* out2 = out1 + 524288;

    // large scratch lives in the dead-after-preA adjacency buffer (A head)
    char* Ab = (char*)d_in[2];
    float*          hA      = (float*)(Ab + 0);              // 1 MiB
    float*          hB      = (float*)(Ab + 1048576);        // 1 MiB
    unsigned short* hT      = (unsigned short*)(Ab + 2097152); // 512 KiB
    float*          Wc      = (float*)(Ab + 2621440);        // 240 KiB
    float*          bc      = (float*)(Ab + 2867200);        // 3.84 KiB
    float*          neipart = (float*)(Ab + 4194304);        // 8 MiB (8 eighths)
    float*          deg     = (float*)(Ab + 13107200);       // 32 KiB
    float*          invdeg  = (float*)(Ab + 13139968);       // 32 KiB

    unsigned long long* mask;
    int wsok = (ws_size >= 8388608) ? 1 : 0;
    if (wsok){
        mask = (unsigned long long*)d_ws;           // 8 MiB in workspace
        k_preA<<<dim3(8192), dim3(256), 0, stream>>>(A, mask, 0);
    } else {
        // A-tail fallback: descending phases; LDS-staged k_preA makes the
        // row-7936..8191 overlay safe.
        mask = (unsigned long long*)(Ab + 260046848);
        k_preA<<<dim3(1),    dim3(256), 0, stream>>>(A, mask, 8191);
        k_preA<<<dim3(7),    dim3(256), 0, stream>>>(A, mask, 8184);
        k_preA<<<dim3(248),  dim3(256), 0, stream>>>(A, mask, 7936);
        k_preA<<<dim3(7936), dim3(256), 0, stream>>>(A, mask, 0);
    }
    k_deg<<<dim3(2048), dim3(256), 0, stream>>>((const unsigned*)mask, deg, invdeg);
    k_setup<<<dim3(1268), dim3(256), 0, stream>>>(af, atom_emb, msgW, msgb,
        Wih, bih, hA, hT, Wc, bc);

    float* hin = hA; float* hout = hB;
    for (int d = 0; d < DEPTHN; ++d){
        k_nei<<<dim3(512), dim3(256), 0, stream>>>(hT, (const unsigned*)mask, neipart);
        k_gru<<<dim3(128), dim3(512), 0, stream>>>(hin, hout, neipart, invdeg, deg,
            Wc + d*6144, bc + d*96, bih + d*96, bhh + d*96, Whh + d*3072,
            hT, out0, (d == DEPTHN-1) ? 1 : 0);
        float* tmp = hin; hin = hout; hout = tmp;
    }
    k_bond<<<dim3(2048), dim3(256), 0, stream>>>(bfe, bond_emb, out1);
    k_pool<<<dim3(256), dim3(256), 0, stream>>>(hin, bidx, poolW, poolb, out2);
}